// Round 16
// baseline (297.546 us; speedup 1.0000x reference)
//
#include <hip/hip_runtime.h>

#define VOCAB 8192
#define DIM   256
#define NTOK  32768          // 8*4096

// d_out layout (floats): quantised[8388608], loss, codebook_loss, idx[32768] (as float)
#define LOSS_OFF 8388608
#define CB_OFF   8388609
#define IDX_OFF  8388610

// ---- ws layout (bytes) ----
#define X2_F     0            // float[32768]   (f32 index)
#define E2_F     32768        // float[8192]
#define ACC_F    40960        // float (fallback loss acc)
#define OVF_I    40961        // int
#define BEST_B   196608       // u64[32768]   -> ends 458752
#define EMB16_B  458752       // bf16[8192*256] = 4 MiB (af-order layout) -> ends 4653056
#define SMAX_B   4718592      // float[256][32768] = 32 MiB
#define SCNT_B   38273024     // int[256]
#define BIN_B    38404096     // u32[256][CAP_S]
#define CAP_S    8192         // per-stile bucket capacity (expected ~280)
#define PSUM_B   46792704     // float[2048] per-block loss partials
#define WS_NEED  (PSUM_B + 8192 * 4)   // 46,825,472 bytes

#define M2 1.5e-4f            // dot-space rescue margin (err budget ~6e-5 practical)
#define LCAP 4096             // per-block LDS candidate cap (expected ~280)

typedef __attribute__((ext_vector_type(8)))  short bf16x8;
typedef __attribute__((ext_vector_type(16))) float f32x16;

// ===========================================================================
// k_sums: numpy pairwise-exact x2/e2 (proven round 3) + fused emb->bf16 cvt
// into AF-ORDER layout: byte = (c>>5)*16384 + kt*1024 + ((c&31)+h*32)*16
// (one wave-load in k_coarse = 1 KB contiguous). + init of per-launch state.
__global__ __launch_bounds__(256) void k_sums(const float* __restrict__ x,
                                              const float* __restrict__ emb,
                                              float* __restrict__ ws,
                                              unsigned long long* __restrict__ best,
                                              int* __restrict__ scnt,
                                              unsigned* __restrict__ e16u,
                                              int full) {
    const int lane = threadIdx.x & 63;
    const int wave = threadIdx.x >> 6;
    const int row  = blockIdx.x * 16 + wave * 4 + (lane >> 4);
    const int sub  = lane & 15;
    const int k    = sub & 7;
    const int half = sub >> 3;
    const float* src = (row < NTOK ? x + (size_t)row * DIM
                                   : emb + (size_t)(row - NTOK) * DIM)
                       + half * 128 + k;
    float r;
    {
        float v0 = src[0];
        float t0 = v0 * v0;
        asm volatile("" : "+v"(t0));     // block fma contraction
        r = t0;
        for (int i = 1; i < 16; ++i) {
            float w = src[8 * i];
            float u = w * w;
            asm volatile("" : "+v"(u));
            r = r + u;
        }
    }
    float t;
    t = __shfl_xor(r, 1, 64); r = r + t;
    t = __shfl_xor(r, 2, 64); r = r + t;
    t = __shfl_xor(r, 4, 64); r = r + t;
    t = __shfl_xor(r, 8, 64); r = r + t;
    if (sub == 0) ws[row] = r;

    // fused k_cvt into af-order layout (truncate to bf16)
    if (full && row >= NTOK) {
        const int c = row - NTOK;
        const float* er = emb + (size_t)c * DIM + sub * 16;   // elems sub*16..+15 (kt=sub)
        const float4 f0 = *(const float4*)(er + 0);
        const float4 f1 = *(const float4*)(er + 4);
        const float4 f2 = *(const float4*)(er + 8);
        const float4 f3 = *(const float4*)(er + 12);
        uint4 u0, u1;
        u0.x = (__float_as_uint(f0.y) & 0xFFFF0000u) | (__float_as_uint(f0.x) >> 16);
        u0.y = (__float_as_uint(f0.w) & 0xFFFF0000u) | (__float_as_uint(f0.z) >> 16);
        u0.z = (__float_as_uint(f1.y) & 0xFFFF0000u) | (__float_as_uint(f1.x) >> 16);
        u0.w = (__float_as_uint(f1.w) & 0xFFFF0000u) | (__float_as_uint(f1.z) >> 16);
        u1.x = (__float_as_uint(f2.y) & 0xFFFF0000u) | (__float_as_uint(f2.x) >> 16);
        u1.y = (__float_as_uint(f2.w) & 0xFFFF0000u) | (__float_as_uint(f2.z) >> 16);
        u1.z = (__float_as_uint(f3.y) & 0xFFFF0000u) | (__float_as_uint(f3.x) >> 16);
        u1.w = (__float_as_uint(f3.w) & 0xFFFF0000u) | (__float_as_uint(f3.z) >> 16);
        unsigned* dst = e16u + (((size_t)(c >> 5) * 16384 + (size_t)sub * 1024
                               + (size_t)(c & 31) * 16) >> 2);
        *(uint4*)dst         = u0;      // h=0: elems kt*16+0..7
        *(uint4*)(dst + 128) = u1;      // h=1: elems kt*16+8..15 (+512 B)
    }

    const int gid = blockIdx.x * 256 + threadIdx.x;
    if (gid == 0) {
        ws[ACC_F] = 0.0f;
        ((int*)ws)[OVF_I] = 0;
    }
    if (full) {
        if (gid < NTOK) best[gid] = ~0ULL;
        if (gid < 256)  scnt[gid] = 0;
    }
}

// ===========================================================================
// k_coarse v5b: barrier-free register streaming + 4 independent acc chains.
// CORRECTNESS FIX vs v5: chains hold PARTIAL SUMS over disjoint K-slices, so
// the merge is element-wise SUM (acc*a[q]+acc*b[q]) BEFORE the max tree —
// not max-of-halves (round-15 bug, K-loop accumulator rule).
__device__ __forceinline__ unsigned f_ord(float v) {
    unsigned u = __float_as_uint(v);
    return u ^ ((unsigned)((int)u >> 31) | 0x80000000u);
}
__device__ __forceinline__ float f_unord(unsigned k) {
    unsigned m = (k >> 31) ? 0x80000000u : 0xFFFFFFFFu;
    return __uint_as_float(k ^ m);
}

__global__ __launch_bounds__(512, 2) void k_coarse(
        const float* __restrict__ x, const unsigned short* __restrict__ embh,
        float* __restrict__ smax,
        unsigned* __restrict__ binned, int* __restrict__ scnt,
        int* __restrict__ ovf) {
    __shared__ unsigned tmax[128];
    __shared__ float tthr[128];
    __shared__ unsigned lbuf[2 + LCAP];
    __shared__ unsigned lcnt[256], lbase[256], lcur[256];

    const int tid  = threadIdx.x;
    const int lane = tid & 63, wid = tid >> 6;
    const int g = wid & 1, csub = wid >> 1;
    const int t_wave = blockIdx.x * 128 + g * 64;

    // ---- persistent x B-frags: bx[grp][kt], token col = lane&31, k = kt*16+(lane>>5)*8+j
    bf16x8 bx[2][16];
    {
        const int tok0 = t_wave + (lane & 31);
#pragma unroll
        for (int grp = 0; grp < 2; ++grp) {
            const float* xr = x + (size_t)(tok0 + grp * 32) * DIM + (lane >> 5) * 8;
#pragma unroll
            for (int kt = 0; kt < 16; ++kt) {
                float4 f0 = *(const float4*)(xr + kt * 16);
                float4 f1 = *(const float4*)(xr + kt * 16 + 4);
                union { bf16x8 v; unsigned u[4]; } P;
                P.u[0] = (__float_as_uint(f0.y) & 0xFFFF0000u) | (__float_as_uint(f0.x) >> 16);
                P.u[1] = (__float_as_uint(f0.w) & 0xFFFF0000u) | (__float_as_uint(f0.z) >> 16);
                P.u[2] = (__float_as_uint(f1.y) & 0xFFFF0000u) | (__float_as_uint(f1.x) >> 16);
                P.u[3] = (__float_as_uint(f1.w) & 0xFFFF0000u) | (__float_as_uint(f1.z) >> 16);
                bx[grp][kt] = P.v;
            }
        }
    }

    // af stream base: chunk n covers codeblocks n*4+csub; lane-contiguous 1KB loads
    const char* ep = (const char*)embh + (size_t)csub * 16384 + (size_t)lane * 16;

    bf16x8 afA[8], afB[8];
#pragma unroll
    for (int j = 0; j < 8; ++j)
        afA[j] = *(const bf16x8*)(ep + j * 1024);

    float rmax = -3.0e38f;
    for (int n = 0; n < 64; ++n) {
        // load half1 (kt 8..15) of this chunk
        const char* epB = ep + 8192;
#pragma unroll
        for (int j = 0; j < 8; ++j)
            afB[j] = *(const bf16x8*)(epB + j * 1024);

        f32x16 acc0a, acc0b, acc1a, acc1b;
#pragma unroll
        for (int q = 0; q < 16; ++q) {
            acc0a[q] = 0.0f; acc0b[q] = 0.0f; acc1a[q] = 0.0f; acc1b[q] = 0.0f;
        }

        __builtin_amdgcn_s_setprio(1);
#pragma unroll
        for (int j = 0; j < 8; j += 2) {   // even j -> a chains, odd j -> b chains
            acc0a = __builtin_amdgcn_mfma_f32_32x32x16_bf16(afA[j],     bx[0][j],     acc0a, 0, 0, 0);
            acc1a = __builtin_amdgcn_mfma_f32_32x32x16_bf16(afA[j],     bx[1][j],     acc1a, 0, 0, 0);
            acc0b = __builtin_amdgcn_mfma_f32_32x32x16_bf16(afA[j + 1], bx[0][j + 1], acc0b, 0, 0, 0);
            acc1b = __builtin_amdgcn_mfma_f32_32x32x16_bf16(afA[j + 1], bx[1][j + 1], acc1b, 0, 0, 0);
        }
        __builtin_amdgcn_s_setprio(0);

        // prefetch half0 (kt 0..7) of next chunk
        const char* epn = ep + 65536;
        if (n < 63) {
#pragma unroll
            for (int j = 0; j < 8; ++j)
                afA[j] = *(const bf16x8*)(epn + j * 1024);
        }

        __builtin_amdgcn_s_setprio(1);
#pragma unroll
        for (int j = 0; j < 8; j += 2) {
            acc0a = __builtin_amdgcn_mfma_f32_32x32x16_bf16(afB[j],     bx[0][8 + j],     acc0a, 0, 0, 0);
            acc1a = __builtin_amdgcn_mfma_f32_32x32x16_bf16(afB[j],     bx[1][8 + j],     acc1a, 0, 0, 0);
            acc0b = __builtin_amdgcn_mfma_f32_32x32x16_bf16(afB[j + 1], bx[0][8 + j + 1], acc0b, 0, 0, 0);
            acc1b = __builtin_amdgcn_mfma_f32_32x32x16_bf16(afB[j + 1], bx[1][8 + j + 1], acc1b, 0, 0, 0);
        }
        __builtin_amdgcn_s_setprio(0);
        ep = epn;

        // MERGE: full dot = a-chain + b-chain (disjoint K-slices), THEN max
        float m0, m1;
        {
            float s0 = acc0a[0] + acc0b[0],  s1 = acc0a[1] + acc0b[1];
            float s2 = acc0a[2] + acc0b[2],  s3 = acc0a[3] + acc0b[3];
            float s4 = acc0a[4] + acc0b[4],  s5 = acc0a[5] + acc0b[5];
            float s6 = acc0a[6] + acc0b[6],  s7 = acc0a[7] + acc0b[7];
            float s8 = acc0a[8] + acc0b[8],  s9 = acc0a[9] + acc0b[9];
            float sA = acc0a[10] + acc0b[10], sB = acc0a[11] + acc0b[11];
            float sC = acc0a[12] + acc0b[12], sD = acc0a[13] + acc0b[13];
            float sE = acc0a[14] + acc0b[14], sF = acc0a[15] + acc0b[15];
            float a = fmaxf(fmaxf(s0, s1), fmaxf(s2, s3));
            float b = fmaxf(fmaxf(s4, s5), fmaxf(s6, s7));
            float c = fmaxf(fmaxf(s8, s9), fmaxf(sA, sB));
            float d = fmaxf(fmaxf(sC, sD), fmaxf(sE, sF));
            m0 = fmaxf(fmaxf(a, b), fmaxf(c, d));
            s0 = acc1a[0] + acc1b[0];  s1 = acc1a[1] + acc1b[1];
            s2 = acc1a[2] + acc1b[2];  s3 = acc1a[3] + acc1b[3];
            s4 = acc1a[4] + acc1b[4];  s5 = acc1a[5] + acc1b[5];
            s6 = acc1a[6] + acc1b[6];  s7 = acc1a[7] + acc1b[7];
            s8 = acc1a[8] + acc1b[8];  s9 = acc1a[9] + acc1b[9];
            sA = acc1a[10] + acc1b[10]; sB = acc1a[11] + acc1b[11];
            sC = acc1a[12] + acc1b[12]; sD = acc1a[13] + acc1b[13];
            sE = acc1a[14] + acc1b[14]; sF = acc1a[15] + acc1b[15];
            a = fmaxf(fmaxf(s0, s1), fmaxf(s2, s3));
            b = fmaxf(fmaxf(s4, s5), fmaxf(s6, s7));
            c = fmaxf(fmaxf(s8, s9), fmaxf(sA, sB));
            d = fmaxf(fmaxf(sC, sD), fmaxf(sE, sF));
            m1 = fmaxf(fmaxf(a, b), fmaxf(c, d));
        }
        m0 = fmaxf(m0, __shfl_xor(m0, 32, 64));
        m1 = fmaxf(m1, __shfl_xor(m1, 32, 64));
        const float mv = (lane < 32) ? m0 : m1;      // token = t_wave + lane
        rmax = fmaxf(rmax, mv);
        smax[(size_t)(n * 4 + csub) * NTOK + t_wave + lane] = mv;
    }

    // ---- per-token threshold = gmax - M2 (cross-wave merge in LDS)
    if (tid < 128) tmax[tid] = 0u;
    if (tid == 0) lbuf[0] = 0u;
    if (tid < 256) { lcnt[tid] = 0u; lcur[tid] = 0u; }
    __syncthreads();
    atomicMax(&tmax[g * 64 + lane], f_ord(rmax));
    __syncthreads();
    if (tid < 128) tthr[tid] = f_unord(tmax[tid]) - M2;
    __syncthreads();

    // ---- collect own 32768 cells into LDS list
    const int t0b = blockIdx.x * 128;
    for (int r = 0; r < 64; ++r) {
        const int cell  = r * 512 + tid;       // 0..32767
        const int stile = cell >> 7, tl = cell & 127;
        const float v = smax[(size_t)stile * NTOK + t0b + tl];
        if (v >= tthr[tl]) {
            const unsigned p = atomicAdd(&lbuf[0], 1u);
            if (p < LCAP)
                lbuf[2 + p] = ((unsigned)(t0b + tl) << 8) | (unsigned)stile;
        }
    }
    __syncthreads();
    unsigned bc = lbuf[0];
    if (bc > LCAP) { bc = LCAP; if (tid == 0) *ovf = 1; }

    // ---- direct bucket emission: LDS histogram -> per-stile base -> scatter
    for (unsigned i = tid; i < bc; i += 512)
        atomicAdd(&lcnt[lbuf[2 + i] & 255u], 1u);
    __syncthreads();
    if (tid < 256 && lcnt[tid]) {
        const unsigned b = (unsigned)atomicAdd(&scnt[tid], (int)lcnt[tid]);
        lbase[tid] = b;
        if (b + lcnt[tid] > CAP_S) *ovf = 1;
    }
    __syncthreads();
    for (unsigned i = tid; i < bc; i += 512) {
        const unsigned e = lbuf[2 + i];
        const unsigned s = e & 255u;
        const unsigned p = lbase[s] + atomicAdd(&lcur[s], 1u);
        if (p < CAP_S) binned[(size_t)s * CAP_S + p] = e;
    }
}

// ===========================================================================
// k_exact2: per-stile buckets, emb tile in LDS, ref-bit-identical fp32 score
__device__ __forceinline__ float exact_score(const float* __restrict__ xr,
                                             const float* __restrict__ er,
                                             float x2t, float e2v) {
    float dot = 0.0f;
#pragma unroll 16
    for (int d = 0; d < DIM; d += 4) {
        const float4 e4 = *(const float4*)(er + d);
        const float4 x4 = *(const float4*)(xr + d);
        dot = fmaf(e4.x, x4.x, dot);
        dot = fmaf(e4.y, x4.y, dot);
        dot = fmaf(e4.z, x4.z, dot);
        dot = fmaf(e4.w, x4.w, dot);
    }
    const float A = x2t + e2v;          // fl(x2 + e2)
    return A - 2.0f * dot;              // fl(A - fl(2*dot)); 2*dot exact
}

__global__ __launch_bounds__(256) void k_exact2(
        const float* __restrict__ x, const float* __restrict__ emb,
        const float* __restrict__ x2, const float* __restrict__ e2,
        const unsigned* __restrict__ binned, const int* __restrict__ scnt,
        const int* __restrict__ ovf, unsigned long long* __restrict__ best) {
    __shared__ float elds[32][257];
    __shared__ float e2s[32];
    const int s = blockIdx.x >> 3, sub = blockIdx.x & 7;
    {   // stage this stile's 32 emb rows (fp32) into LDS
        const int r = threadIdx.x >> 3, c0 = (threadIdx.x & 7) * 32;
        const float* er = emb + (size_t)(s * 32 + r) * DIM + c0;
#pragma unroll
        for (int q = 0; q < 8; ++q) {
            const float4 f = *(const float4*)(er + q * 4);
            elds[r][c0 + q * 4 + 0] = f.x; elds[r][c0 + q * 4 + 1] = f.y;
            elds[r][c0 + q * 4 + 2] = f.z; elds[r][c0 + q * 4 + 3] = f.w;
        }
        if (threadIdx.x < 32) e2s[threadIdx.x] = e2[s * 32 + threadIdx.x];
    }
    __syncthreads();

    const int lane = threadIdx.x & 63, wave = threadIdx.x >> 6;
    const int l5 = lane & 31, half = lane >> 5;
    int count = scnt[s]; if (count > CAP_S) count = CAP_S;
    const unsigned* bucket = binned + (size_t)s * CAP_S;
    const float e2v = e2s[l5];

    for (int k = (sub * 4 + wave) * 2 + half; k < count; k += 64) {
        const unsigned e = bucket[k];
        const int token  = (int)(e >> 8);
        const float* xr  = x + (size_t)token * DIM;
        const float x2t  = x2[token];
        // sequential fmaf chain, d ascending, x/y/z/w order == proven ref semantics
        float dot = 0.0f;
#pragma unroll 16
        for (int d = 0; d < DIM; d += 4) {
            const float4 x4 = *(const float4*)(xr + d);
            dot = fmaf(elds[l5][d + 0], x4.x, dot);
            dot = fmaf(elds[l5][d + 1], x4.y, dot);
            dot = fmaf(elds[l5][d + 2], x4.z, dot);
            dot = fmaf(elds[l5][d + 3], x4.w, dot);
        }
        const float A  = x2t + e2v;
        const float sc = A - 2.0f * dot;
        unsigned long long pk =
            ((unsigned long long)__float_as_uint(sc) << 32) | (unsigned)(s * 32 + l5);
#pragma unroll
        for (int m = 1; m < 32; m <<= 1) {   // stays within the 32-lane half
            unsigned long long o = __shfl_xor(pk, m, 64);
            if (o < pk) pk = o;
        }
        if (l5 == 0) atomicMin(&best[token], pk);
    }

    if (*ovf) {   // exhaustive safety net (never expected)
        const size_t stride = (size_t)2048 * 256;
        for (size_t c = blockIdx.x * 256 + threadIdx.x;
             c < (size_t)NTOK * VOCAB; c += stride) {
            const int token = (int)(c >> 13);
            const int v     = (int)(c & (VOCAB - 1));
            const float sc = exact_score(x + (size_t)token * DIM, emb + (size_t)v * DIM,
                                         x2[token], e2[v]);
            unsigned long long pk =
                ((unsigned long long)__float_as_uint(sc) << 32) | (unsigned)v;
            atomicMin(&best[token], pk);
        }
    }
}

// ===========================================================================
// FALLBACK (round-3 proven path) — used when ws_size < WS_NEED; writes idxf
__global__ __launch_bounds__(512) void k_main_fb(
        const float* __restrict__ x, const float* __restrict__ emb,
        const float* __restrict__ x2, const float* __restrict__ e2,
        float* __restrict__ idxf) {
    __shared__ float xT[32][132];
    __shared__ float eT[32][260];
    const int tid = threadIdx.x;
    const int tx = tid & 31, ty = tid >> 5;
    const int t0 = blockIdx.x * 128;
    float x2r[8];
#pragma unroll
    for (int ii = 0; ii < 8; ++ii)
        x2r[ii] = x2[t0 + ((ii & 4) << 4) + ty * 4 + (ii & 3)];
    float tb[8]; int ti[8];
#pragma unroll
    for (int s = 0; s < 8; ++s) { tb[s] = 3.0e38f; ti[s] = 0; }
    const int xt = tid & 127, xc = tid >> 7;
    const int ev = tid & 255, ec0 = tid >> 8;
    for (int v0 = 0; v0 < VOCAB; v0 += 256) {
        float a[8][8];
#pragma unroll
        for (int i = 0; i < 8; ++i)
#pragma unroll
            for (int j = 0; j < 8; ++j) a[i][j] = 0.0f;
        for (int kk = 0; kk < DIM; kk += 32) {
            __syncthreads();
#pragma unroll
            for (int h = 0; h < 2; ++h) {
                const int kc = h * 16 + xc * 4;
                const float4 vx = *(const float4*)&x[(size_t)(t0 + xt) * DIM + kk + kc];
                xT[kc + 0][xt] = vx.x; xT[kc + 1][xt] = vx.y;
                xT[kc + 2][xt] = vx.z; xT[kc + 3][xt] = vx.w;
            }
#pragma unroll
            for (int h = 0; h < 4; ++h) {
                const int kc = (ec0 + 2 * h) * 4;
                const float4 ve = *(const float4*)&emb[(size_t)(v0 + ev) * DIM + kk + kc];
                eT[kc + 0][ev] = ve.x; eT[kc + 1][ev] = ve.y;
                eT[kc + 2][ev] = ve.z; eT[kc + 3][ev] = ve.w;
            }
            __syncthreads();
#pragma unroll 4
            for (int k = 0; k < 32; ++k) {
                float xa[8], eb[8];
                *(float4*)&xa[0] = *(const float4*)&xT[k][ty * 4];
                *(float4*)&xa[4] = *(const float4*)&xT[k][64 + ty * 4];
                *(float4*)&eb[0] = *(const float4*)&eT[k][tx * 4];
                *(float4*)&eb[4] = *(const float4*)&eT[k][128 + tx * 4];
#pragma unroll
                for (int i = 0; i < 8; ++i)
#pragma unroll
                    for (int j = 0; j < 8; ++j)
                        a[i][j] = fmaf(xa[i], eb[j], a[i][j]);
            }
        }
#pragma unroll
        for (int jj = 0; jj < 8; ++jj) {
            const int v = v0 + ((jj & 4) << 5) + tx * 4 + (jj & 3);
            const float evv = e2[v];
#pragma unroll
            for (int ii = 0; ii < 8; ++ii) {
                const float A  = x2r[ii] + evv;
                const float sc = A - 2.0f * a[ii][jj];
                if (sc < tb[ii]) { tb[ii] = sc; ti[ii] = v; }
            }
        }
    }
#pragma unroll
    for (int ii = 0; ii < 8; ++ii) {
        float b = tb[ii]; int bi = ti[ii];
#pragma unroll
        for (int m = 1; m < 32; m <<= 1) {
            const float ob = __shfl_xor(b, m, 64);
            const int   oi = __shfl_xor(bi, m, 64);
            if (ob < b || (ob == b && oi < bi)) { b = ob; bi = oi; }
        }
        if (tx == 0) {
            const int token = t0 + ((ii & 4) << 4) + ty * 4 + (ii & 3);
            idxf[token] = (float)bi;
        }
    }
}

// ===========================================================================
// k_gather: idx extraction + quantised gather + loss partials; 2048 blocks,
// grid-stride x4, per-block psum, no atomics/fences in the full path
__global__ __launch_bounds__(256) void k_gather(
        const float* __restrict__ x, const float* __restrict__ emb,
        const unsigned long long* __restrict__ best,
        float* __restrict__ out, float* __restrict__ psum,
        float* __restrict__ acc, int full) {
    const int lane = threadIdx.x & 63;
    float* idxf = out + IDX_OFF;
    float bsum = 0.0f;
#pragma unroll
    for (int it = 0; it < 4; ++it) {
        const int token = (it * 2048 + blockIdx.x) * 4 + (threadIdx.x >> 6);
        int v;
        if (full) {
            v = (int)(unsigned)(best[token] & 0xFFFFFFFFULL);
            if (lane == 0) idxf[token] = (float)v;
        } else {
            v = (int)idxf[token];
        }
        const float4 e4 = *(const float4*)&emb[(size_t)v * DIM + lane * 4];
        const float4 x4 = *(const float4*)&x[(size_t)token * DIM + lane * 4];
        *(float4*)&out[(size_t)token * DIM + lane * 4] = e4;
        const float dx = e4.x - x4.x, dy = e4.y - x4.y;
        const float dz = e4.z - x4.z, dw = e4.w - x4.w;
        bsum += dx*dx + dy*dy + dz*dz + dw*dw;
    }
#pragma unroll
    for (int m = 1; m < 64; m <<= 1) bsum += __shfl_xor(bsum, m, 64);
    __shared__ float wsum[4];
    if (lane == 0) wsum[threadIdx.x >> 6] = bsum;
    __syncthreads();
    if (threadIdx.x == 0) {
        const float s = wsum[0] + wsum[1] + wsum[2] + wsum[3];
        if (full) psum[blockIdx.x] = s;         // no atomic, no fence
        else      atomicAdd(acc, s);            // fallback (perf-irrelevant)
    }
}

// ===========================================================================
// k_final: reduce 2048 per-block partials (full) or read acc (fallback)
__global__ __launch_bounds__(256) void k_final(const float* __restrict__ psum,
                                               const float* __restrict__ acc,
                                               float* __restrict__ out, int full) {
    float s = 0.0f;
    if (full) {
        for (int i = threadIdx.x; i < 2048; i += 256) s += psum[i];
#pragma unroll
        for (int m = 1; m < 64; m <<= 1) s += __shfl_xor(s, m, 64);
        __shared__ float wsum[4];
        if ((threadIdx.x & 63) == 0) wsum[threadIdx.x >> 6] = s;
        __syncthreads();
        s = wsum[0] + wsum[1] + wsum[2] + wsum[3];
    } else {
        s = *acc;
    }
    if (threadIdx.x == 0) {
        const float cb = s * (1.0f / 8388608.0f);
        out[LOSS_OFF] = 1.25f * cb;           // codebook + 0.25*e_latent
        out[CB_OFF]   = cb;
    }
}

// ===========================================================================
extern "C" void kernel_launch(void* const* d_in, const int* in_sizes, int n_in,
                              void* d_out, int out_size, void* d_ws, size_t ws_size,
                              hipStream_t stream) {
    const float* x   = (const float*)d_in[0];
    const float* emb = (const float*)d_in[1];
    float* out  = (float*)d_out;
    char*  wsB  = (char*)d_ws;
    float* wsF  = (float*)d_ws;

    float* x2   = wsF + X2_F;
    float* e2   = wsF + E2_F;
    float* acc  = wsF + ACC_F;
    int*   ovf  = (int*)wsF + OVF_I;
    unsigned long long* best = (unsigned long long*)(wsB + BEST_B);
    unsigned short*     e16  = (unsigned short*)(wsB + EMB16_B);
    float*              smax = (float*)(wsB + SMAX_B);
    int*                scnt = (int*)(wsB + SCNT_B);
    unsigned*           binned = (unsigned*)(wsB + BIN_B);
    float*              psum = (float*)(wsB + PSUM_B);
    float* idxf = out + IDX_OFF;

    const int full = (ws_size >= (size_t)WS_NEED) ? 1 : 0;

    k_sums<<<(NTOK + VOCAB) / 16, 256, 0, stream>>>(x, emb, wsF, best, scnt,
                                                    (unsigned*)e16, full);
    if (full) {
        k_coarse<<<256, 512, 0, stream>>>(x, e16, smax, binned, scnt, ovf);
        k_exact2<<<2048, 256, 0, stream>>>(x, emb, x2, e2, binned, scnt, ovf, best);
    } else {
        k_main_fb<<<NTOK / 128, 512, 0, stream>>>(x, emb, x2, e2, idxf);
    }
    k_gather<<<2048, 256, 0, stream>>>(x, emb, best, out, psum, acc, full);
    k_final <<<1, 256, 0, stream>>>(psum, acc, out, full);
}

// Round 17
// 283.846 us; speedup vs baseline: 1.0483x; 1.0483x over previous
//
#include <hip/hip_runtime.h>

#define VOCAB 8192
#define DIM   256
#define NTOK  32768          // 8*4096

// d_out layout (floats): quantised[8388608], loss, codebook_loss, idx[32768] (as float)
#define LOSS_OFF 8388608
#define CB_OFF   8388609
#define IDX_OFF  8388610

// ---- ws layout (bytes) ----
#define X2_F     0            // float[32768]   (f32 index)
#define E2_F     32768        // float[8192]
#define ACC_F    40960        // float (fallback loss acc)
#define OVF_I    40961        // int
#define BEST_B   196608       // u64[32768]   -> ends 458752
#define EMB16_B  458752       // bf16[8192*256] = 4 MiB (af-order layout) -> ends 4653056
#define SMAX_B   4718592      // float[256][32768] = 32 MiB
#define SCNT_B   38273024     // int[256]
#define BIN_B    38404096     // u32[256][CAP_S]
#define CAP_S    8192         // per-stile bucket capacity (expected ~280)
#define PSUM_B   46792704     // float[8192] per-block loss partials
#define WS_NEED  (PSUM_B + 8192 * 4)   // 46,825,472 bytes

#define M2 1.5e-4f            // dot-space rescue margin (err budget ~6e-5 practical)
#define LCAP 16000            // per-block LDS candidate cap

typedef __attribute__((ext_vector_type(8)))  short bf16x8;
typedef __attribute__((ext_vector_type(16))) float f32x16;

// ===========================================================================
// k_sums: numpy pairwise-exact x2/e2 (proven round 3) + fused emb->bf16 cvt
// into AF-ORDER layout: byte = (c>>5)*16384 + kt*1024 + ((c&31)+h*32)*16
// (one wave-load in k_coarse = 1 KB contiguous). + init of per-launch state.
__global__ __launch_bounds__(256) void k_sums(const float* __restrict__ x,
                                              const float* __restrict__ emb,
                                              float* __restrict__ ws,
                                              unsigned long long* __restrict__ best,
                                              int* __restrict__ scnt,
                                              unsigned* __restrict__ e16u,
                                              int full) {
    const int lane = threadIdx.x & 63;
    const int wave = threadIdx.x >> 6;
    const int row  = blockIdx.x * 16 + wave * 4 + (lane >> 4);
    const int sub  = lane & 15;
    const int k    = sub & 7;
    const int half = sub >> 3;
    const float* src = (row < NTOK ? x + (size_t)row * DIM
                                   : emb + (size_t)(row - NTOK) * DIM)
                       + half * 128 + k;
    float r;
    {
        float v0 = src[0];
        float t0 = v0 * v0;
        asm volatile("" : "+v"(t0));     // block fma contraction
        r = t0;
        for (int i = 1; i < 16; ++i) {
            float w = src[8 * i];
            float u = w * w;
            asm volatile("" : "+v"(u));
            r = r + u;
        }
    }
    float t;
    t = __shfl_xor(r, 1, 64); r = r + t;
    t = __shfl_xor(r, 2, 64); r = r + t;
    t = __shfl_xor(r, 4, 64); r = r + t;
    t = __shfl_xor(r, 8, 64); r = r + t;
    if (sub == 0) ws[row] = r;

    // fused k_cvt into af-order layout (truncate to bf16)
    if (full && row >= NTOK) {
        const int c = row - NTOK;
        const float* er = emb + (size_t)c * DIM + sub * 16;   // elems sub*16..+15 (kt=sub)
        const float4 f0 = *(const float4*)(er + 0);
        const float4 f1 = *(const float4*)(er + 4);
        const float4 f2 = *(const float4*)(er + 8);
        const float4 f3 = *(const float4*)(er + 12);
        uint4 u0, u1;
        u0.x = (__float_as_uint(f0.y) & 0xFFFF0000u) | (__float_as_uint(f0.x) >> 16);
        u0.y = (__float_as_uint(f0.w) & 0xFFFF0000u) | (__float_as_uint(f0.z) >> 16);
        u0.z = (__float_as_uint(f1.y) & 0xFFFF0000u) | (__float_as_uint(f1.x) >> 16);
        u0.w = (__float_as_uint(f1.w) & 0xFFFF0000u) | (__float_as_uint(f1.z) >> 16);
        u1.x = (__float_as_uint(f2.y) & 0xFFFF0000u) | (__float_as_uint(f2.x) >> 16);
        u1.y = (__float_as_uint(f2.w) & 0xFFFF0000u) | (__float_as_uint(f2.z) >> 16);
        u1.z = (__float_as_uint(f3.y) & 0xFFFF0000u) | (__float_as_uint(f3.x) >> 16);
        u1.w = (__float_as_uint(f3.w) & 0xFFFF0000u) | (__float_as_uint(f3.z) >> 16);
        unsigned* dst = e16u + (((size_t)(c >> 5) * 16384 + (size_t)sub * 1024
                               + (size_t)(c & 31) * 16) >> 2);
        *(uint4*)dst         = u0;      // h=0: elems kt*16+0..7
        *(uint4*)(dst + 128) = u1;      // h=1: elems kt*16+8..15 (+512 B)
    }

    const int gid = blockIdx.x * 256 + threadIdx.x;
    if (gid == 0) {
        ws[ACC_F] = 0.0f;
        ((int*)ws)[OVF_I] = 0;
    }
    if (full) {
        if (gid < NTOK) best[gid] = ~0ULL;
        if (gid < 256)  scnt[gid] = 0;
    }
}

// ===========================================================================
// k_coarse v4 (round-14 best, 171 us / ~803 TF): BARRIER-FREE register
// streaming (AITER buffer_load⇄MFMA pattern). 256 blocks x 512 threads,
// 8 waves (g, csub), bx[2][16] persistent; af fragments loaded
// global(L2)->VGPR, software-pipelined afA/afB; compiler inserts counted
// vmcnts. No LDS staging, no main-loop barriers. Tail: collect + buckets.
__device__ __forceinline__ unsigned f_ord(float v) {
    unsigned u = __float_as_uint(v);
    return u ^ ((unsigned)((int)u >> 31) | 0x80000000u);
}
__device__ __forceinline__ float f_unord(unsigned k) {
    unsigned m = (k >> 31) ? 0x80000000u : 0xFFFFFFFFu;
    return __uint_as_float(k ^ m);
}

__global__ __launch_bounds__(512, 2) void k_coarse(
        const float* __restrict__ x, const unsigned short* __restrict__ embh,
        float* __restrict__ smax,
        unsigned* __restrict__ binned, int* __restrict__ scnt,
        int* __restrict__ ovf) {
    __shared__ unsigned tmax[128];
    __shared__ float tthr[128];
    __shared__ unsigned lbuf[2 + LCAP];
    __shared__ unsigned lcnt[256], lbase[256], lcur[256];

    const int tid  = threadIdx.x;
    const int lane = tid & 63, wid = tid >> 6;
    const int g = wid & 1, csub = wid >> 1;
    const int t_wave = blockIdx.x * 128 + g * 64;

    // ---- persistent x B-frags: bx[grp][kt], token col = lane&31, k = kt*16+(lane>>5)*8+j
    bf16x8 bx[2][16];
    {
        const int tok0 = t_wave + (lane & 31);
#pragma unroll
        for (int grp = 0; grp < 2; ++grp) {
            const float* xr = x + (size_t)(tok0 + grp * 32) * DIM + (lane >> 5) * 8;
#pragma unroll
            for (int kt = 0; kt < 16; ++kt) {
                float4 f0 = *(const float4*)(xr + kt * 16);
                float4 f1 = *(const float4*)(xr + kt * 16 + 4);
                union { bf16x8 v; unsigned u[4]; } P;
                P.u[0] = (__float_as_uint(f0.y) & 0xFFFF0000u) | (__float_as_uint(f0.x) >> 16);
                P.u[1] = (__float_as_uint(f0.w) & 0xFFFF0000u) | (__float_as_uint(f0.z) >> 16);
                P.u[2] = (__float_as_uint(f1.y) & 0xFFFF0000u) | (__float_as_uint(f1.x) >> 16);
                P.u[3] = (__float_as_uint(f1.w) & 0xFFFF0000u) | (__float_as_uint(f1.z) >> 16);
                bx[grp][kt] = P.v;
            }
        }
    }

    // af stream base: chunk n covers codeblocks n*4+csub; lane-contiguous 1KB loads
    const char* ep = (const char*)embh + (size_t)csub * 16384 + (size_t)lane * 16;

    bf16x8 afA[8], afB[8];
#pragma unroll
    for (int j = 0; j < 8; ++j)
        afA[j] = *(const bf16x8*)(ep + j * 1024);

    float rmax = -3.0e38f;
    for (int n = 0; n < 64; ++n) {
        // load half1 (kt 8..15) of this chunk
        const char* epB = ep + 8192;
#pragma unroll
        for (int j = 0; j < 8; ++j)
            afB[j] = *(const bf16x8*)(epB + j * 1024);

        f32x16 acc0, acc1;
#pragma unroll
        for (int q = 0; q < 16; ++q) { acc0[q] = 0.0f; acc1[q] = 0.0f; }

        __builtin_amdgcn_s_setprio(1);
#pragma unroll
        for (int j = 0; j < 8; ++j) {
            acc0 = __builtin_amdgcn_mfma_f32_32x32x16_bf16(afA[j], bx[0][j], acc0, 0, 0, 0);
            acc1 = __builtin_amdgcn_mfma_f32_32x32x16_bf16(afA[j], bx[1][j], acc1, 0, 0, 0);
        }
        __builtin_amdgcn_s_setprio(0);

        // prefetch half0 (kt 0..7) of next chunk
        const char* epn = ep + 65536;
        if (n < 63) {
#pragma unroll
            for (int j = 0; j < 8; ++j)
                afA[j] = *(const bf16x8*)(epn + j * 1024);
        }

        __builtin_amdgcn_s_setprio(1);
#pragma unroll
        for (int j = 0; j < 8; ++j) {
            acc0 = __builtin_amdgcn_mfma_f32_32x32x16_bf16(afB[j], bx[0][8 + j], acc0, 0, 0, 0);
            acc1 = __builtin_amdgcn_mfma_f32_32x32x16_bf16(afB[j], bx[1][8 + j], acc1, 0, 0, 0);
        }
        __builtin_amdgcn_s_setprio(0);
        ep = epn;

        float m0, m1;
        {
            float a = fmaxf(fmaxf(acc0[0], acc0[1]),  fmaxf(acc0[2], acc0[3]));
            float b = fmaxf(fmaxf(acc0[4], acc0[5]),  fmaxf(acc0[6], acc0[7]));
            float c = fmaxf(fmaxf(acc0[8], acc0[9]),  fmaxf(acc0[10], acc0[11]));
            float d = fmaxf(fmaxf(acc0[12], acc0[13]),fmaxf(acc0[14], acc0[15]));
            m0 = fmaxf(fmaxf(a, b), fmaxf(c, d));
            a = fmaxf(fmaxf(acc1[0], acc1[1]),  fmaxf(acc1[2], acc1[3]));
            b = fmaxf(fmaxf(acc1[4], acc1[5]),  fmaxf(acc1[6], acc1[7]));
            c = fmaxf(fmaxf(acc1[8], acc1[9]),  fmaxf(acc1[10], acc1[11]));
            d = fmaxf(fmaxf(acc1[12], acc1[13]),fmaxf(acc1[14], acc1[15]));
            m1 = fmaxf(fmaxf(a, b), fmaxf(c, d));
        }
        m0 = fmaxf(m0, __shfl_xor(m0, 32, 64));
        m1 = fmaxf(m1, __shfl_xor(m1, 32, 64));
        const float mv = (lane < 32) ? m0 : m1;      // token = t_wave + lane
        rmax = fmaxf(rmax, mv);
        smax[(size_t)(n * 4 + csub) * NTOK + t_wave + lane] = mv;
    }

    // ---- per-token threshold = gmax - M2 (cross-wave merge in LDS)
    if (tid < 128) tmax[tid] = 0u;
    if (tid == 0) lbuf[0] = 0u;
    if (tid < 256) { lcnt[tid] = 0u; lcur[tid] = 0u; }
    __syncthreads();
    atomicMax(&tmax[g * 64 + lane], f_ord(rmax));
    __syncthreads();
    if (tid < 128) tthr[tid] = f_unord(tmax[tid]) - M2;
    __syncthreads();

    // ---- collect own 32768 cells into LDS list
    const int t0b = blockIdx.x * 128;
    for (int r = 0; r < 64; ++r) {
        const int cell  = r * 512 + tid;       // 0..32767
        const int stile = cell >> 7, tl = cell & 127;
        const float v = smax[(size_t)stile * NTOK + t0b + tl];
        if (v >= tthr[tl]) {
            const unsigned p = atomicAdd(&lbuf[0], 1u);
            if (p < LCAP)
                lbuf[2 + p] = ((unsigned)(t0b + tl) << 8) | (unsigned)stile;
        }
    }
    __syncthreads();
    unsigned bc = lbuf[0];
    if (bc > LCAP) { bc = LCAP; if (tid == 0) *ovf = 1; }

    // ---- direct bucket emission: LDS histogram -> per-stile base -> scatter
    for (unsigned i = tid; i < bc; i += 512)
        atomicAdd(&lcnt[lbuf[2 + i] & 255u], 1u);
    __syncthreads();
    if (tid < 256 && lcnt[tid]) {
        const unsigned b = (unsigned)atomicAdd(&scnt[tid], (int)lcnt[tid]);
        lbase[tid] = b;
        if (b + lcnt[tid] > CAP_S) *ovf = 1;
    }
    __syncthreads();
    for (unsigned i = tid; i < bc; i += 512) {
        const unsigned e = lbuf[2 + i];
        const unsigned s = e & 255u;
        const unsigned p = lbase[s] + atomicAdd(&lcur[s], 1u);
        if (p < CAP_S) binned[(size_t)s * CAP_S + p] = e;
    }
}

// ===========================================================================
// k_exact2: per-stile buckets, emb tile in LDS, ref-bit-identical fp32 score
__device__ __forceinline__ float exact_score(const float* __restrict__ xr,
                                             const float* __restrict__ er,
                                             float x2t, float e2v) {
    float dot = 0.0f;
#pragma unroll 16
    for (int d = 0; d < DIM; d += 4) {
        const float4 e4 = *(const float4*)(er + d);
        const float4 x4 = *(const float4*)(xr + d);
        dot = fmaf(e4.x, x4.x, dot);
        dot = fmaf(e4.y, x4.y, dot);
        dot = fmaf(e4.z, x4.z, dot);
        dot = fmaf(e4.w, x4.w, dot);
    }
    const float A = x2t + e2v;          // fl(x2 + e2)
    return A - 2.0f * dot;              // fl(A - fl(2*dot)); 2*dot exact
}

__global__ __launch_bounds__(256) void k_exact2(
        const float* __restrict__ x, const float* __restrict__ emb,
        const float* __restrict__ x2, const float* __restrict__ e2,
        const unsigned* __restrict__ binned, const int* __restrict__ scnt,
        const int* __restrict__ ovf, unsigned long long* __restrict__ best) {
    __shared__ float elds[32][257];
    __shared__ float e2s[32];
    const int s = blockIdx.x >> 3, sub = blockIdx.x & 7;
    {   // stage this stile's 32 emb rows (fp32) into LDS
        const int r = threadIdx.x >> 3, c0 = (threadIdx.x & 7) * 32;
        const float* er = emb + (size_t)(s * 32 + r) * DIM + c0;
#pragma unroll
        for (int q = 0; q < 8; ++q) {
            const float4 f = *(const float4*)(er + q * 4);
            elds[r][c0 + q * 4 + 0] = f.x; elds[r][c0 + q * 4 + 1] = f.y;
            elds[r][c0 + q * 4 + 2] = f.z; elds[r][c0 + q * 4 + 3] = f.w;
        }
        if (threadIdx.x < 32) e2s[threadIdx.x] = e2[s * 32 + threadIdx.x];
    }
    __syncthreads();

    const int lane = threadIdx.x & 63, wave = threadIdx.x >> 6;
    const int l5 = lane & 31, half = lane >> 5;
    int count = scnt[s]; if (count > CAP_S) count = CAP_S;
    const unsigned* bucket = binned + (size_t)s * CAP_S;
    const float e2v = e2s[l5];

    for (int k = (sub * 4 + wave) * 2 + half; k < count; k += 64) {
        const unsigned e = bucket[k];
        const int token  = (int)(e >> 8);
        const float* xr  = x + (size_t)token * DIM;
        const float x2t  = x2[token];
        // sequential fmaf chain, d ascending, x/y/z/w order == proven ref semantics
        float dot = 0.0f;
#pragma unroll 16
        for (int d = 0; d < DIM; d += 4) {
            const float4 x4 = *(const float4*)(xr + d);
            dot = fmaf(elds[l5][d + 0], x4.x, dot);
            dot = fmaf(elds[l5][d + 1], x4.y, dot);
            dot = fmaf(elds[l5][d + 2], x4.z, dot);
            dot = fmaf(elds[l5][d + 3], x4.w, dot);
        }
        const float A  = x2t + e2v;
        const float sc = A - 2.0f * dot;
        unsigned long long pk =
            ((unsigned long long)__float_as_uint(sc) << 32) | (unsigned)(s * 32 + l5);
#pragma unroll
        for (int m = 1; m < 32; m <<= 1) {   // stays within the 32-lane half
            unsigned long long o = __shfl_xor(pk, m, 64);
            if (o < pk) pk = o;
        }
        if (l5 == 0) atomicMin(&best[token], pk);
    }

    if (*ovf) {   // exhaustive safety net (never expected)
        const size_t stride = (size_t)2048 * 256;
        for (size_t c = blockIdx.x * 256 + threadIdx.x;
             c < (size_t)NTOK * VOCAB; c += stride) {
            const int token = (int)(c >> 13);
            const int v     = (int)(c & (VOCAB - 1));
            const float sc = exact_score(x + (size_t)token * DIM, emb + (size_t)v * DIM,
                                         x2[token], e2[v]);
            unsigned long long pk =
                ((unsigned long long)__float_as_uint(sc) << 32) | (unsigned)v;
            atomicMin(&best[token], pk);
        }
    }
}

// ===========================================================================
// FALLBACK (round-3 proven path) — used when ws_size < WS_NEED; writes idxf
__global__ __launch_bounds__(512) void k_main_fb(
        const float* __restrict__ x, const float* __restrict__ emb,
        const float* __restrict__ x2, const float* __restrict__ e2,
        float* __restrict__ idxf) {
    __shared__ float xT[32][132];
    __shared__ float eT[32][260];
    const int tid = threadIdx.x;
    const int tx = tid & 31, ty = tid >> 5;
    const int t0 = blockIdx.x * 128;
    float x2r[8];
#pragma unroll
    for (int ii = 0; ii < 8; ++ii)
        x2r[ii] = x2[t0 + ((ii & 4) << 4) + ty * 4 + (ii & 3)];
    float tb[8]; int ti[8];
#pragma unroll
    for (int s = 0; s < 8; ++s) { tb[s] = 3.0e38f; ti[s] = 0; }
    const int xt = tid & 127, xc = tid >> 7;
    const int ev = tid & 255, ec0 = tid >> 8;
    for (int v0 = 0; v0 < VOCAB; v0 += 256) {
        float a[8][8];
#pragma unroll
        for (int i = 0; i < 8; ++i)
#pragma unroll
            for (int j = 0; j < 8; ++j) a[i][j] = 0.0f;
        for (int kk = 0; kk < DIM; kk += 32) {
            __syncthreads();
#pragma unroll
            for (int h = 0; h < 2; ++h) {
                const int kc = h * 16 + xc * 4;
                const float4 vx = *(const float4*)&x[(size_t)(t0 + xt) * DIM + kk + kc];
                xT[kc + 0][xt] = vx.x; xT[kc + 1][xt] = vx.y;
                xT[kc + 2][xt] = vx.z; xT[kc + 3][xt] = vx.w;
            }
#pragma unroll
            for (int h = 0; h < 4; ++h) {
                const int kc = (ec0 + 2 * h) * 4;
                const float4 ve = *(const float4*)&emb[(size_t)(v0 + ev) * DIM + kk + kc];
                eT[kc + 0][ev] = ve.x; eT[kc + 1][ev] = ve.y;
                eT[kc + 2][ev] = ve.z; eT[kc + 3][ev] = ve.w;
            }
            __syncthreads();
#pragma unroll 4
            for (int k = 0; k < 32; ++k) {
                float xa[8], eb[8];
                *(float4*)&xa[0] = *(const float4*)&xT[k][ty * 4];
                *(float4*)&xa[4] = *(const float4*)&xT[k][64 + ty * 4];
                *(float4*)&eb[0] = *(const float4*)&eT[k][tx * 4];
                *(float4*)&eb[4] = *(const float4*)&eT[k][128 + tx * 4];
#pragma unroll
                for (int i = 0; i < 8; ++i)
#pragma unroll
                    for (int j = 0; j < 8; ++j)
                        a[i][j] = fmaf(xa[i], eb[j], a[i][j]);
            }
        }
#pragma unroll
        for (int jj = 0; jj < 8; ++jj) {
            const int v = v0 + ((jj & 4) << 5) + tx * 4 + (jj & 3);
            const float evv = e2[v];
#pragma unroll
            for (int ii = 0; ii < 8; ++ii) {
                const float A  = x2r[ii] + evv;
                const float sc = A - 2.0f * a[ii][jj];
                if (sc < tb[ii]) { tb[ii] = sc; ti[ii] = v; }
            }
        }
    }
#pragma unroll
    for (int ii = 0; ii < 8; ++ii) {
        float b = tb[ii]; int bi = ti[ii];
#pragma unroll
        for (int m = 1; m < 32; m <<= 1) {
            const float ob = __shfl_xor(b, m, 64);
            const int   oi = __shfl_xor(bi, m, 64);
            if (ob < b || (ob == b && oi < bi)) { b = ob; bi = oi; }
        }
        if (tx == 0) {
            const int token = t0 + ((ii & 4) << 4) + ty * 4 + (ii & 3);
            idxf[token] = (float)bi;
        }
    }
}

// ===========================================================================
// k_gather: idx extraction + quantised gather + loss partials (no atomics,
// no fences in the full path — per-block psum slot; k_final reduces)
__global__ __launch_bounds__(256) void k_gather(
        const float* __restrict__ x, const float* __restrict__ emb,
        const unsigned long long* __restrict__ best,
        float* __restrict__ out, float* __restrict__ psum,
        float* __restrict__ acc, int full) {
    const int token = blockIdx.x * 4 + (threadIdx.x >> 6);
    const int lane  = threadIdx.x & 63;
    float* idxf = out + IDX_OFF;
    int v;
    if (full) {
        v = (int)(unsigned)(best[token] & 0xFFFFFFFFULL);
        if (lane == 0) idxf[token] = (float)v;
    } else {
        v = (int)idxf[token];
    }
    const float4 e4 = *(const float4*)&emb[(size_t)v * DIM + lane * 4];
    const float4 x4 = *(const float4*)&x[(size_t)token * DIM + lane * 4];
    *(float4*)&out[(size_t)token * DIM + lane * 4] = e4;
    const float dx = e4.x - x4.x, dy = e4.y - x4.y, dz = e4.z - x4.z, dw = e4.w - x4.w;
    float s = dx*dx + dy*dy + dz*dz + dw*dw;
#pragma unroll
    for (int m = 1; m < 64; m <<= 1) s += __shfl_xor(s, m, 64);
    __shared__ float wsum[4];
    if (lane == 0) wsum[threadIdx.x >> 6] = s;
    __syncthreads();
    if (threadIdx.x == 0) {
        const float bsum = wsum[0] + wsum[1] + wsum[2] + wsum[3];
        if (full) psum[blockIdx.x] = bsum;      // no atomic, no fence
        else      atomicAdd(acc, bsum);         // fallback (perf-irrelevant)
    }
}

// ===========================================================================
// k_final: reduce 8192 per-block partials (full) or read acc (fallback)
__global__ __launch_bounds__(256) void k_final(const float* __restrict__ psum,
                                               const float* __restrict__ acc,
                                               float* __restrict__ out, int full) {
    float s = 0.0f;
    if (full) {
        for (int i = threadIdx.x; i < 8192; i += 256) s += psum[i];
#pragma unroll
        for (int m = 1; m < 64; m <<= 1) s += __shfl_xor(s, m, 64);
        __shared__ float wsum[4];
        if ((threadIdx.x & 63) == 0) wsum[threadIdx.x >> 6] = s;
        __syncthreads();
        s = wsum[0] + wsum[1] + wsum[2] + wsum[3];
    } else {
        s = *acc;
    }
    if (threadIdx.x == 0) {
        const float cb = s * (1.0f / 8388608.0f);
        out[LOSS_OFF] = 1.25f * cb;           // codebook + 0.25*e_latent
        out[CB_OFF]   = cb;
    }
}

// ===========================================================================
extern "C" void kernel_launch(void* const* d_in, const int* in_sizes, int n_in,
                              void* d_out, int out_size, void* d_ws, size_t ws_size,
                              hipStream_t stream) {
    const float* x   = (const float*)d_in[0];
    const float* emb = (const float*)d_in[1];
    float* out  = (float*)d_out;
    char*  wsB  = (char*)d_ws;
    float* wsF  = (float*)d_ws;

    float* x2   = wsF + X2_F;
    float* e2   = wsF + E2_F;
    float* acc  = wsF + ACC_F;
    int*   ovf  = (int*)wsF + OVF_I;
    unsigned long long* best = (unsigned long long*)(wsB + BEST_B);
    unsigned short*     e16  = (unsigned short*)(wsB + EMB16_B);
    float*              smax = (float*)(wsB + SMAX_B);
    int*                scnt = (int*)(wsB + SCNT_B);
    unsigned*           binned = (unsigned*)(wsB + BIN_B);
    float*              psum = (float*)(wsB + PSUM_B);
    float* idxf = out + IDX_OFF;

    const int full = (ws_size >= (size_t)WS_NEED) ? 1 : 0;

    k_sums<<<(NTOK + VOCAB) / 16, 256, 0, stream>>>(x, emb, wsF, best, scnt,
                                                    (unsigned*)e16, full);
    if (full) {
        k_coarse<<<256, 512, 0, stream>>>(x, e16, smax, binned, scnt, ovf);
        k_exact2<<<2048, 256, 0, stream>>>(x, emb, x2, e2, binned, scnt, ovf, best);
    } else {
        k_main_fb<<<NTOK / 128, 512, 0, stream>>>(x, emb, x2, e2, idxf);
    }
    k_gather<<<NTOK / 4, 256, 0, stream>>>(x, emb, best, out, psum, acc, full);
    k_final <<<1, 256, 0, stream>>>(psum, acc, out, full);
}